// Round 3
// baseline (374.071 us; speedup 1.0000x reference)
//
#include <hip/hip_runtime.h>

#define N_NODES 50000
#define N_EDGES 800000
#define GRID_E  800512          // N_EDGES + max padding (8 buckets x 64)
#define K_BR    8
#define SCAN_BLOCKS 196         // ceil(50000/256)

// ---------------- workspace layout (bytes) ----------------
// fbuf      : GRID_E*128 B   @ 0            (102,465,536)  [slotLocal overlaid @0, dead before mlp]
// perm      : GRID_E ints    @ 102,465,536  (3,202,048)
// posOfSlot : E ints         @ 105,667,584  (3,200,000)
// cnt(deg)  : N ints         @ 108,867,584  (200,000)
// bucketCnt : 8 ints         @ 109,067,584
// bucketCur : 8 ints         @ 109,067,616
// nodeStart : N ints         @ 109,067,712  (200,000)
// blockSums : 256 ints       @ 109,267,712
// blockOffs : 256 ints       @ 109,268,736
// W1T       : 9216 floats    @ 109,269,760  (36,864)  [k][o][c]
// W2T       : 8192 floats    @ 109,306,624  (32,768)  [k][g][o]
// total: 109,339,392  (< proven ws floor 109,473,920)

__device__ __forceinline__ int branch_idx(float dx, float dy) {
    return (dx > 0.0f ? 1 : 0) + (dy > 0.0f ? 2 : 0) +
           ((fabsf(dx) - fabsf(dy)) > 0.0f ? 4 : 0);
}

__global__ void transpose_kernel(const float* __restrict__ W1, const float* __restrict__ W2,
                                 float* __restrict__ W1T, float* __restrict__ W2T) {
    int t = blockIdx.x * blockDim.x + threadIdx.x;
    if (t < K_BR * 36 * 32) {
        int k = t / 1152, r = t % 1152;
        int c = r / 32, o = r % 32;
        W1T[k * 1152 + o * 36 + c] = W1[t];
    } else {
        int u = t - K_BR * 36 * 32;  // grid sized exactly, u < 8192
        int k = u / 1024, r = u % 1024;
        int o = r / 32, g = r % 32;
        W2T[k * 1024 + g * 32 + o] = W2[u];
    }
}

// pass1: branch histogram + per-target rank (the ONLY per-edge global atomic pass)
__global__ void pass1_kernel(const int* __restrict__ ei, const float* __restrict__ pos,
                             int* __restrict__ cnt, int* __restrict__ slotLocal,
                             int* __restrict__ bucketCnt) {
    __shared__ int h[K_BR];
    int t = threadIdx.x;
    if (t < K_BR) h[t] = 0;
    __syncthreads();
    int e = blockIdx.x * blockDim.x + t;
    if (e < N_EDGES) {
        int s = ei[e], d = ei[N_EDGES + e];
        float dx = pos[2 * s] - pos[2 * d];
        float dy = pos[2 * s + 1] - pos[2 * d + 1];
        atomicAdd(&h[branch_idx(dx, dy)], 1);
        slotLocal[e] = atomicAdd(&cnt[d], 1);
    }
    __syncthreads();
    if (t < K_BR && h[t] > 0) atomicAdd(&bucketCnt[t], h[t]);
}

// ---- hierarchical exclusive scan of cnt[N] -> nodeStart[N] ----
__global__ void scanA_kernel(const int* __restrict__ cnt, int* __restrict__ nodeStart,
                             int* __restrict__ blockSums) {
    __shared__ int s[256];
    int t = threadIdx.x;
    int i = blockIdx.x * 256 + t;
    int v = (i < N_NODES) ? cnt[i] : 0;
    s[t] = v;
    __syncthreads();
#pragma unroll
    for (int off = 1; off < 256; off <<= 1) {
        int tmp = (t >= off) ? s[t - off] : 0;
        __syncthreads();
        s[t] += tmp;
        __syncthreads();
    }
    if (i < N_NODES) nodeStart[i] = s[t] - v;  // exclusive
    if (t == 255) blockSums[blockIdx.x] = s[255];
}

// scanB also derives the (64-aligned) bucket base cursors
__global__ void scanB_kernel(const int* __restrict__ blockSums, int* __restrict__ blockOffs,
                             const int* __restrict__ bucketCnt, int* __restrict__ bucketCur) {
    __shared__ int s[256];
    int t = threadIdx.x;
    int v = (t < SCAN_BLOCKS) ? blockSums[t] : 0;
    s[t] = v;
    __syncthreads();
#pragma unroll
    for (int off = 1; off < 256; off <<= 1) {
        int tmp = (t >= off) ? s[t - off] : 0;
        __syncthreads();
        s[t] += tmp;
        __syncthreads();
    }
    blockOffs[t] = s[t] - v;
    if (t == 0) {
        int off = 0;
        for (int k = 0; k < K_BR; ++k) {
            bucketCur[k] = off;
            off = (off + bucketCnt[k] + 63) & ~63;  // 64-align next bucket
        }
    }
}

__global__ void scanC_kernel(int* __restrict__ nodeStart, const int* __restrict__ blockOffs) {
    int i = blockIdx.x * 256 + threadIdx.x;
    if (i < N_NODES) nodeStart[i] += blockOffs[blockIdx.x];
}

// scatter: no per-edge global atomics (8 per block). Writes perm + inverse map.
__global__ void scatter_kernel(const int* __restrict__ ei, const float* __restrict__ pos,
                               const int* __restrict__ slotLocal, const int* __restrict__ nodeStart,
                               int* __restrict__ bucketCur, int* __restrict__ perm,
                               int* __restrict__ posOfSlot) {
    __shared__ int h[K_BR];
    __shared__ int base[K_BR];
    int t = threadIdx.x;
    if (t < K_BR) h[t] = 0;
    __syncthreads();
    int e = blockIdx.x * blockDim.x + t;
    int idx = 0, rank = 0, d = 0;
    bool valid = e < N_EDGES;
    if (valid) {
        int s = ei[e];
        d = ei[N_EDGES + e];
        float dx = pos[2 * s] - pos[2 * d];
        float dy = pos[2 * s + 1] - pos[2 * d + 1];
        idx = branch_idx(dx, dy);
        rank = atomicAdd(&h[idx], 1);
    }
    __syncthreads();
    if (t < K_BR) base[t] = (h[t] > 0) ? atomicAdd(&bucketCur[t], h[t]) : 0;
    __syncthreads();
    if (valid) {
        int tt = base[idx] + rank;
        perm[tt] = e | (idx << 24);
        posOfSlot[nodeStart[d] + slotLocal[e]] = tt;
    }
}

__global__ void __launch_bounds__(256) mlp_kernel(
    const int* __restrict__ perm, const int* __restrict__ ei,
    const float* __restrict__ x, const float* __restrict__ ea,
    const float* __restrict__ ew,
    const float* __restrict__ W1T, const float* __restrict__ b1,
    const float* __restrict__ W2T, const float* __restrict__ b2,
    float* __restrict__ fbuf) {
    int t = blockIdx.x * blockDim.x + threadIdx.x;
    int p = perm[t];
    // bucket spans are 64-aligned and filled contiguously from the start, so
    // if lane 0 of a wave is padding (-1), the whole wave is padding.
    int p0 = __builtin_amdgcn_readfirstlane(p);
    if (p0 < 0) return;
    int k = (p0 >> 24) & 7;  // wave-uniform branch id -> weights become s_loads
    bool valid = p >= 0;
    int e = valid ? (p & 0xFFFFFF) : (p0 & 0xFFFFFF);

    int s = ei[e];
    int d = ei[N_EDGES + e];

    float m[36];
    const float4* xj = (const float4*)(x + 32 * (size_t)s);
    const float4* xi = (const float4*)(x + 32 * (size_t)d);
#pragma unroll
    for (int q = 0; q < 8; ++q) {
        float4 a = xj[q], b = xi[q];
        m[4 * q + 0] = a.x - b.x;
        m[4 * q + 1] = a.y - b.y;
        m[4 * q + 2] = a.z - b.z;
        m[4 * q + 3] = a.w - b.w;
    }
    float4 eav = ((const float4*)ea)[e];
    m[32] = eav.x; m[33] = eav.y; m[34] = eav.z; m[35] = eav.w;
    float w = ew[e];

    const float* w1  = W1T + k * (32 * 36);
    const float* bb1 = b1 + k * 32;
    float h[32];
#pragma unroll
    for (int o = 0; o < 32; ++o) {
        float acc = bb1[o];
#pragma unroll
        for (int c = 0; c < 36; ++c) acc = fmaf(m[c], w1[o * 36 + c], acc);
        h[o] = fmaxf(acc, 0.0f);
    }

    const float* w2  = W2T + k * 1024;
    const float* bb2 = b2 + k * 32;
    // store to OWN perm position -> waves write contiguous, fully-dirtied lines
    float4* frow = (float4*)(fbuf + 32 * (size_t)t);
#pragma unroll
    for (int go = 0; go < 8; ++go) {
        float4 r;
#pragma unroll
        for (int gi = 0; gi < 4; ++gi) {
            int g = go * 4 + gi;
            float acc = bb2[g];
#pragma unroll
            for (int o = 0; o < 32; ++o) acc = fmaf(h[o], w2[g * 32 + o], acc);
            (&r.x)[gi] = fmaxf(acc, 0.0f) * w;
        }
        frow[go] = r;  // pad lanes write garbage to their own pad row: never read
    }
}

__global__ void agg_kernel(const float* __restrict__ fbuf, const int* __restrict__ posOfSlot,
                           const int* __restrict__ nodeStart, const int* __restrict__ deg,
                           const float* __restrict__ x, const float* __restrict__ Wr,
                           const float* __restrict__ br, float* __restrict__ out) {
    int t = blockIdx.x * blockDim.x + threadIdx.x;
    if (t >= N_NODES * 32) return;
    int n = t >> 5, o = t & 31;
    int st = nodeStart[n], dg = deg[n];
    float acc = 0.0f;
    for (int j = 0; j < dg; ++j) {
        int pos = posOfSlot[st + j];          // broadcast across the 32 lanes of node n
        acc += fbuf[(size_t)pos * 32 + o];    // gathered 128B row, coalesced per node
    }
    float inv = 1.0f / (float)max(dg, 1);
    acc = acc * inv + br[o];
    const float* xr = x + 32 * (size_t)n;
#pragma unroll
    for (int c = 0; c < 32; ++c) acc = fmaf(xr[c], Wr[c * 32 + o], acc);
    out[t] = acc;
}

extern "C" void kernel_launch(void* const* d_in, const int* in_sizes, int n_in,
                              void* d_out, int out_size, void* d_ws, size_t ws_size,
                              hipStream_t stream) {
    const float* x   = (const float*)d_in[0];
    const float* pos = (const float*)d_in[1];
    const int*   ei  = (const int*)d_in[2];
    const float* ea  = (const float*)d_in[3];
    const float* ew  = (const float*)d_in[4];
    const float* W1  = (const float*)d_in[5];
    const float* b1  = (const float*)d_in[6];
    const float* W2  = (const float*)d_in[7];
    const float* b2  = (const float*)d_in[8];
    const float* Wr  = (const float*)d_in[9];
    const float* br  = (const float*)d_in[10];
    float* out = (float*)d_out;

    char* ws = (char*)d_ws;
    float* fbuf      = (float*)(ws + 0);
    int*   slotLocal = (int*)(ws + 0);              // overlaid: dead before fbuf written
    int*   perm      = (int*)(ws + 102465536);
    int*   posOfSlot = (int*)(ws + 105667584);
    int*   cnt       = (int*)(ws + 108867584);      // degree after pass1
    int*   bucketCnt = (int*)(ws + 109067584);
    int*   bucketCur = (int*)(ws + 109067616);
    int*   nodeStart = (int*)(ws + 109067712);
    int*   blockSums = (int*)(ws + 109267712);
    int*   blockOffs = (int*)(ws + 109268736);
    float* W1T       = (float*)(ws + 109269760);
    float* W2T       = (float*)(ws + 109306624);

    hipMemsetAsync(cnt, 0, 200064, stream);                  // cnt + bucketCnt + bucketCur
    hipMemsetAsync(perm, 0xFF, GRID_E * 4, stream);          // all -1 (pad sentinel)

    transpose_kernel<<<68, 256, 0, stream>>>(W1, W2, W1T, W2T);
    pass1_kernel<<<N_EDGES / 256, 256, 0, stream>>>(ei, pos, cnt, slotLocal, bucketCnt);
    scanA_kernel<<<SCAN_BLOCKS, 256, 0, stream>>>(cnt, nodeStart, blockSums);
    scanB_kernel<<<1, 256, 0, stream>>>(blockSums, blockOffs, bucketCnt, bucketCur);
    scanC_kernel<<<SCAN_BLOCKS, 256, 0, stream>>>(nodeStart, blockOffs);
    scatter_kernel<<<N_EDGES / 256, 256, 0, stream>>>(ei, pos, slotLocal, nodeStart,
                                                      bucketCur, perm, posOfSlot);
    mlp_kernel<<<GRID_E / 256, 256, 0, stream>>>(perm, ei, x, ea, ew,
                                                 W1T, b1, W2T, b2, fbuf);
    agg_kernel<<<(N_NODES * 32 + 255) / 256, 256, 0, stream>>>(fbuf, posOfSlot, nodeStart,
                                                               cnt, x, Wr, br, out);
}